// Round 3
// baseline (169.875 us; speedup 1.0000x reference)
//
#include <hip/hip_runtime.h>

typedef float f32x4 __attribute__((ext_vector_type(4)));
typedef short s16x8 __attribute__((ext_vector_type(8)));
typedef unsigned short u16;
typedef u16 u16x4v __attribute__((ext_vector_type(4)));
typedef u16 u16x8v __attribute__((ext_vector_type(8)));

#define NB 4
#define NN 2048
#define DI 512
#define DOUTC 512
#define KP 3

__device__ __forceinline__ u16 f2b(float f) {
  unsigned u = __builtin_bit_cast(unsigned, f);
  unsigned r = u + 0x7fffu + ((u >> 16) & 1u);
  return (u16)(r >> 16);
}

// ---------------- prep kernels ----------------
__global__ void prep_uv(const float* __restrict__ Wv, const float* __restrict__ aw,
                        const float* __restrict__ bk, float* u, float* v, float* bsum) {
  int c = blockIdx.x * blockDim.x + threadIdx.x;
  if (c >= DI) return;
  float a1 = 0.f, a2 = 0.f;
  const float* row = Wv + (size_t)c * DOUTC;
  for (int d = 0; d < DOUTC; ++d) {
    float w = row[d];
    a1 += w * aw[d];
    a2 += w * aw[DOUTC + d];
  }
  u[c] = a1; v[c] = a2;
  bsum[c] = bk[c] + bk[DOUTC + c] + bk[2 * DOUTC + c];
}

__global__ void prep_cc(const float* __restrict__ bv, const float* __restrict__ aw,
                        const float* __restrict__ ab, float* cc) {
  int l = threadIdx.x;
  float s = 0.f;
  for (int d = l; d < DOUTC; d += 64) s += bv[d] * (aw[d] + aw[DOUTC + d]);
  for (int o = 32; o; o >>= 1) s += __shfl_down(s, o);
  if (l == 0) cc[0] = s + ab[0];
}

// sj[b,i] = X[b,i,:].u ; si[b,i] = X[b,i,:].v   (one wave per row, f32 inputs)
__global__ void sjsi_kernel(const float* __restrict__ X, const float* __restrict__ u,
                            const float* __restrict__ v, float* sj, float* si) {
  int wid = threadIdx.x >> 6, lane = threadIdx.x & 63;
  int row = blockIdx.x * 4 + wid;
  const f32x4* xr = (const f32x4*)(X + (size_t)row * DI);
  const f32x4* ur = (const f32x4*)u;
  const f32x4* vr = (const f32x4*)v;
  float a1 = 0.f, a2 = 0.f;
#pragma unroll
  for (int t = 0; t < 2; ++t) {
    int f4 = lane + 64 * t;
    f32x4 x = xr[f4], uu = ur[f4], vv = vr[f4];
    a1 += x[0]*uu[0] + x[1]*uu[1] + x[2]*uu[2] + x[3]*uu[3];
    a2 += x[0]*vv[0] + x[1]*vv[1] + x[2]*vv[2] + x[3]*vv[3];
  }
  for (int o = 32; o; o >>= 1) { a1 += __shfl_down(a1, o); a2 += __shfl_down(a2, o); }
  if (!lane) { sj[row] = a1; si[row] = a2; }
}

// tiled transpose -> bf16; optionally also emits the non-transposed bf16 copy.
// per slice: in R x C -> out C x R (and out2 R x C).  grid=(C/64, R/64, slices)
template <typename TI>
__global__ void trans_bf16_k(const TI* __restrict__ in, u16* __restrict__ out,
                             u16* __restrict__ out2, int R, int C) {
  __shared__ u16 tile[64][65];
  const TI* inS = in + (size_t)blockIdx.z * R * C;
  u16* outS = out + (size_t)blockIdx.z * R * C;
  int r0 = blockIdx.y * 64, c0 = blockIdx.x * 64;
  int t = threadIdx.x;
#pragma unroll
  for (int p = 0; p < 4; ++p) {
    int g = t + p * 256;
    int r = g >> 4, c4 = (g & 15) << 2;
    const TI* src = inS + (size_t)(r0 + r) * C + c0 + c4;
    u16x4v bv4;
    if constexpr (sizeof(TI) == 4) {
      f32x4 x = *(const f32x4*)src;
      bv4[0] = f2b(x[0]); bv4[1] = f2b(x[1]); bv4[2] = f2b(x[2]); bv4[3] = f2b(x[3]);
    } else {
      bv4 = *(const u16x4v*)src;
    }
    tile[r][c4+0] = bv4[0]; tile[r][c4+1] = bv4[1];
    tile[r][c4+2] = bv4[2]; tile[r][c4+3] = bv4[3];
    if (out2) {
      *(u16x4v*)(out2 + (size_t)blockIdx.z * R * C + (size_t)(r0 + r) * C + c0 + c4) = bv4;
    }
  }
  __syncthreads();
#pragma unroll
  for (int p = 0; p < 4; ++p) {
    int g = t + p * 256;
    int oc = g >> 4, o4 = (g & 15) << 2;
    u16x4v wv;
    wv[0] = tile[o4+0][oc]; wv[1] = tile[o4+1][oc];
    wv[2] = tile[o4+2][oc]; wv[3] = tile[o4+3][oc];
    *(u16x4v*)(outS + (size_t)(c0 + oc) * R + r0 + o4) = wv;
  }
}

// one wave per row: denom + transition (bf16).  T indexed by (globalRow - rowbase).
__global__ void tmat_kernel(const float* __restrict__ Aa, const float* __restrict__ sj,
                            const float* __restrict__ si, const float* __restrict__ ccp,
                            u16* __restrict__ T, int rowbase) {
  __shared__ float alpha[4][NN];
  int wid = threadIdx.x >> 6, lane = threadIdx.x & 63;
  int lr = blockIdx.x * 4 + wid;
  int gi = rowbase + lr;
  int b = gi >> 11;
  float siv = si[gi] + ccp[0];
  const f32x4* Arow = (const f32x4*)(Aa + (size_t)gi * NN);
  const f32x4* sjr = (const f32x4*)(sj + (size_t)b * NN);
  float sum = 0.f;
#pragma unroll
  for (int t = 0; t < 8; ++t) {
    int f4 = lane + 64 * t;
    f32x4 a = Arow[f4];
    f32x4 s = sjr[f4];
    f32x4 al;
#pragma unroll
    for (int j = 0; j < 4; ++j) {
      float e = s[j] + siv;
      e = e > 0.f ? e : 0.2f * e;
      al[j] = a[j] * __expf(e);
      sum += al[j];
    }
    *(f32x4*)&alpha[wid][4 * f4] = al;
  }
#pragma unroll
  for (int o = 1; o < 64; o <<= 1) sum += __shfl_xor(sum, o);
  float rden = 1.0f / (sum + 1e-12f);
  u16* Trow = T + (size_t)lr * NN;
#pragma unroll
  for (int t = 0; t < 8; ++t) {
    int f4 = lane + 64 * t;
    f32x4 al = *(f32x4*)&alpha[wid][4 * f4];
    u16x4v o4;
#pragma unroll
    for (int j = 0; j < 4; ++j) o4[j] = f2b(al[j] * rden);
    *(u16x4v*)(Trow + 4 * f4) = o4;
  }
}

// ---- GEMM: 128x64 tile, BK=64, 3-buffer pipeline, counted vmcnt, XCD swizzle ----
struct GemmP {
  const u16 *A0, *A1, *A2;   // row-major M x Kc (per source)
  const u16 *B0, *B1, *B2;   // row-major N x Kc  (B transposed)
  const float* bias;
  void* out;
  u16* outT;                 // optional transposed bf16 output (ldOT = M-dim)
  int ldA, ldB, ldO, ldOT;
  size_t batchA, batchB, batchOut, batchOutT;
};

__device__ __forceinline__ void gload16(const u16* g, const u16* l) {
  __builtin_amdgcn_global_load_lds((const __attribute__((address_space(1))) void*)g,
                                   (__attribute__((address_space(3))) void*)l, 16, 0, 0);
}

// chunk-XOR swizzled LDS: global (row, c8) stored at LDS chunk row*8 + (c8 ^ (row&7)).
template <int NSRC, int KT, bool OBF, bool OTR>
__launch_bounds__(256)
__global__ void gemm_k(GemmP p) {
  __shared__ u16 As[3][128 * 64];
  __shared__ u16 Bs[3][64 * 64];
  int tid = threadIdx.x;
  int lane = tid & 63;
  int w = tid >> 6;
  int wr = w >> 1, wc = w & 1;
  // XCD-aware swizzle of the (x,y) plane: each XCD gets one contiguous chunk
  // (shares a single bn => B panel L2-resident).  nxy % 8 == 0 for all our grids.
  unsigned nx = gridDim.x;
  unsigned flat = blockIdx.y * nx + blockIdx.x;
  unsigned cpx = (nx * gridDim.y) >> 3;
  unsigned wg = (flat & 7) * cpx + (flat >> 3);
  int bm = wg % nx, bn = wg / nx, bz = blockIdx.z;
  const u16* Alist[3] = {p.A0, p.A1, p.A2};
  const u16* Blist[3] = {p.B0, p.B1, p.B2};
  int rof = lane & 15, ksel = lane >> 4, sw = lane & 7;
  int wub = (tid & 192) * 8;  // wave-uniform chunk base (elems) within a 256-chunk group
  f32x4 acc[4][2] = {};

  auto stage = [&](int t, int buf) {
    int s = t / KT;
    int k0 = (t - s * KT) * 64;
    const u16* Ag = Alist[s] + (size_t)bz * p.batchA + (size_t)bm * 128 * p.ldA;
    const u16* Bg = Blist[s] + (size_t)bz * p.batchB + (size_t)bn * 64 * p.ldB;
#pragma unroll
    for (int q = 0; q < 4; ++q) {
      int ch = q * 256 + tid;
      int row = ch >> 3;
      int c8 = (ch & 7) ^ (row & 7);
      gload16(Ag + (size_t)row * p.ldA + k0 + c8 * 8, &As[buf][0] + q * 2048 + wub);
    }
#pragma unroll
    for (int q = 0; q < 2; ++q) {
      int ch = q * 256 + tid;
      int row = ch >> 3;
      int c8 = (ch & 7) ^ (row & 7);
      gload16(Bg + (size_t)row * p.ldB + k0 + c8 * 8, &Bs[buf][0] + q * 2048 + wub);
    }
  };

  constexpr int TOT = NSRC * KT;
  stage(0, 0);
  stage(1, 1);
  asm volatile("s_waitcnt vmcnt(6)" ::: "memory");
  __builtin_amdgcn_s_barrier();
  __builtin_amdgcn_sched_barrier(0);

  int bufc = 0;
  for (int t = 0; t < TOT; ++t) {
    int nb = t + 2;
    if (nb < TOT) stage(nb, nb == 2 ? 2 : (nb - 3) % 3);  // nb%3 without slow mod: nb>=3 path
    const u16* Asb = &As[bufc][0];
    const u16* Bsb = &Bs[bufc][0];
#pragma unroll
    for (int kk = 0; kk < 2; ++kk) {
      int csw = ((kk * 4 + ksel) ^ sw) * 8;
      s16x8 af[4], bfr[2];
#pragma unroll
      for (int mf = 0; mf < 4; ++mf) {
        int r = wr * 64 + mf * 16 + rof;
        af[mf] = *(const s16x8*)(Asb + r * 64 + csw);
      }
#pragma unroll
      for (int nf = 0; nf < 2; ++nf) {
        int r = wc * 32 + nf * 16 + rof;
        bfr[nf] = *(const s16x8*)(Bsb + r * 64 + csw);
      }
#pragma unroll
      for (int mf = 0; mf < 4; ++mf)
#pragma unroll
        for (int nf = 0; nf < 2; ++nf)
          acc[mf][nf] = __builtin_amdgcn_mfma_f32_16x16x32_bf16(af[mf], bfr[nf], acc[mf][nf], 0, 0, 0);
    }
    if (nb < TOT) {
      asm volatile("s_waitcnt vmcnt(6)" ::: "memory");
    } else if (t + 1 < TOT) {
      asm volatile("s_waitcnt vmcnt(0)" ::: "memory");
    }
    if (t + 1 < TOT) {
      __builtin_amdgcn_s_barrier();
      __builtin_amdgcn_sched_barrier(0);
    }
    bufc = bufc + 1; if (bufc == 3) bufc = 0;
  }

  int rb = bm * 128 + wr * 64, cb = bn * 64 + wc * 32;
  int rsub = ksel << 2, csub = rof;
  if constexpr (OBF) {
    u16* o = (u16*)p.out + (size_t)bz * p.batchOut;
    u16* oT = OTR ? p.outT + (size_t)bz * p.batchOutT : nullptr;
#pragma unroll
    for (int mf = 0; mf < 4; ++mf)
#pragma unroll
      for (int nf = 0; nf < 2; ++nf) {
        int cidx = cb + nf * 16 + csub;
        u16x4v tv;
#pragma unroll
        for (int r = 0; r < 4; ++r) {
          tv[r] = f2b(acc[mf][nf][r]);
          o[(size_t)(rb + mf * 16 + rsub + r) * p.ldO + cidx] = tv[r];
        }
        if constexpr (OTR) {
          *(u16x4v*)(oT + (size_t)cidx * p.ldOT + rb + mf * 16 + rsub) = tv;
        }
      }
  } else {
    float* o = (float*)p.out + (size_t)bz * p.batchOut;
#pragma unroll
    for (int nf = 0; nf < 2; ++nf) {
      int cidx = cb + nf * 16 + csub;
      float bv_ = p.bias[cidx];
#pragma unroll
      for (int mf = 0; mf < 4; ++mf)
#pragma unroll
        for (int r = 0; r < 4; ++r) {
          float val = acc[mf][nf][r] + bv_;
          o[(size_t)(rb + mf * 16 + rsub + r) * p.ldO + cidx] = val > 0.f ? val : 0.f;
        }
    }
  }
}

// ---------------- launch ----------------
extern "C" void kernel_launch(void* const* d_in, const int* in_sizes, int n_in,
                              void* d_out, int out_size, void* d_ws, size_t ws_size,
                              hipStream_t stream) {
  const float* X  = (const float*)d_in[0];
  const float* A  = (const float*)d_in[1];
  const float* Wv = (const float*)d_in[2];
  const float* bv = (const float*)d_in[3];
  const float* aw = (const float*)d_in[4];
  const float* ab = (const float*)d_in[5];
  const float* Wk = (const float*)d_in[6];
  const float* bk = (const float*)d_in[7];
  float* out = (float*)d_out;

  char* ws = (char*)d_ws;
  size_t off = 0;
  auto alloc = [&](size_t bytes) -> void* {
    void* p = (void*)(ws + off);
    off = (off + bytes + 255) & ~(size_t)255;
    return p;
  };
  float* u    = (float*)alloc(DI * 4);
  float* v    = (float*)alloc(DI * 4);
  float* cc   = (float*)alloc(256);
  float* bsum = (float*)alloc(DOUTC * 4);
  float* sj   = (float*)alloc((size_t)NB * NN * 4);
  float* si   = (float*)alloc((size_t)NB * NN * 4);
  u16* WkT  = (u16*)alloc((size_t)KP * DI * DOUTC * 2);
  u16* Xb   = (u16*)alloc((size_t)NB * NN * DI * 2);
  u16* XbT  = (u16*)alloc((size_t)NB * NN * DI * 2);
  u16* X1b  = (u16*)alloc((size_t)NB * NN * DOUTC * 2);
  u16* X1bT = (u16*)alloc((size_t)NB * NN * DOUTC * 2);
  u16* X2b  = (u16*)alloc((size_t)NB * NN * DOUTC * 2);
  size_t fixedEnd = off;
  int G = 4;
  while (G > 1 && fixedEnd + (size_t)G * NN * NN * 2 > ws_size) G >>= 1;
  u16* Tb = (u16*)alloc((size_t)G * NN * NN * 2);

  prep_uv<<<2, 256, 0, stream>>>(Wv, aw, bk, u, v, bsum);
  prep_cc<<<1, 64, 0, stream>>>(bv, aw, ab, cc);
  trans_bf16_k<float><<<dim3(8, 8, 3), 256, 0, stream>>>(Wk, WkT, nullptr, 512, 512);
  // X: one read -> XbT (transposed bf16) + Xb (row-major bf16)
  trans_bf16_k<float><<<dim3(8, 32, 4), 256, 0, stream>>>(X, XbT, Xb, NN, DI);
  sjsi_kernel<<<NB * NN / 4, 256, 0, stream>>>(X, u, v, sj, si);

  for (int g0 = 0; g0 < NB; g0 += G) {
    tmat_kernel<<<G * NN / 4, 256, 0, stream>>>(A, sj, si, cc, Tb, g0 * NN);

    GemmP p1{};
    p1.A0 = p1.A1 = p1.A2 = Tb;
    p1.B0 = p1.B1 = p1.B2 = XbT + (size_t)g0 * DI * NN;
    p1.bias = nullptr;
    p1.out = X1b + (size_t)g0 * NN * DOUTC;
    p1.outT = X1bT + (size_t)g0 * DOUTC * NN;
    p1.ldA = NN; p1.ldB = NN; p1.ldO = DOUTC; p1.ldOT = NN;
    p1.batchA = (size_t)NN * NN; p1.batchB = (size_t)DI * NN;
    p1.batchOut = (size_t)NN * DOUTC; p1.batchOutT = (size_t)DOUTC * NN;
    gemm_k<1, 32, true, true><<<dim3(16, 8, G), 256, 0, stream>>>(p1);

    GemmP p2 = p1;
    p2.B0 = p2.B1 = p2.B2 = X1bT + (size_t)g0 * DOUTC * NN;
    p2.out = X2b + (size_t)g0 * NN * DOUTC;
    p2.outT = nullptr;
    gemm_k<1, 32, true, false><<<dim3(16, 8, G), 256, 0, stream>>>(p2);
  }

  GemmP p3{};
  p3.A0 = Xb; p3.A1 = X1b; p3.A2 = X2b;
  p3.B0 = WkT; p3.B1 = WkT + (size_t)DI * DOUTC; p3.B2 = WkT + (size_t)2 * DI * DOUTC;
  p3.bias = bsum; p3.out = out; p3.outT = nullptr;
  p3.ldA = DI; p3.ldB = DI; p3.ldO = DOUTC; p3.ldOT = 0;
  p3.batchA = 0; p3.batchB = 0; p3.batchOut = 0; p3.batchOutT = 0;
  gemm_k<3, 8, false, false><<<dim3(64, 8, 1), 256, 0, stream>>>(p3);
}

// Round 4
// 142.114 us; speedup vs baseline: 1.1953x; 1.1953x over previous
//
#include <hip/hip_runtime.h>

typedef float f32x4 __attribute__((ext_vector_type(4)));
typedef short s16x8 __attribute__((ext_vector_type(8)));
typedef unsigned short u16;
typedef u16 u16x4v __attribute__((ext_vector_type(4)));
typedef u16 u16x8v __attribute__((ext_vector_type(8)));

#define NB 4
#define NN 2048
#define DI 512
#define DOUTC 512
#define KP 3

__device__ __forceinline__ u16 f2b(float f) {
  unsigned u = __builtin_bit_cast(unsigned, f);
  unsigned r = u + 0x7fffu + ((u >> 16) & 1u);
  return (u16)(r >> 16);
}

// ---------------- prep kernels ----------------
__global__ void prep_uv(const float* __restrict__ Wv, const float* __restrict__ aw,
                        const float* __restrict__ bk, float* u, float* v, float* bsum) {
  int c = blockIdx.x * blockDim.x + threadIdx.x;
  if (c >= DI) return;
  float a1 = 0.f, a2 = 0.f;
  const float* row = Wv + (size_t)c * DOUTC;
  for (int d = 0; d < DOUTC; ++d) {
    float w = row[d];
    a1 += w * aw[d];
    a2 += w * aw[DOUTC + d];
  }
  u[c] = a1; v[c] = a2;
  bsum[c] = bk[c] + bk[DOUTC + c] + bk[2 * DOUTC + c];
}

__global__ void prep_cc(const float* __restrict__ bv, const float* __restrict__ aw,
                        const float* __restrict__ ab, float* cc) {
  int l = threadIdx.x;
  float s = 0.f;
  for (int d = l; d < DOUTC; d += 64) s += bv[d] * (aw[d] + aw[DOUTC + d]);
  for (int o = 32; o; o >>= 1) s += __shfl_down(s, o);
  if (l == 0) cc[0] = s + ab[0];
}

// sj[b,i] = X[b,i,:].u ; si[b,i] = X[b,i,:].v   (one wave per row, f32 inputs)
__global__ void sjsi_kernel(const float* __restrict__ X, const float* __restrict__ u,
                            const float* __restrict__ v, float* sj, float* si) {
  int wid = threadIdx.x >> 6, lane = threadIdx.x & 63;
  int row = blockIdx.x * 4 + wid;
  const f32x4* xr = (const f32x4*)(X + (size_t)row * DI);
  const f32x4* ur = (const f32x4*)u;
  const f32x4* vr = (const f32x4*)v;
  float a1 = 0.f, a2 = 0.f;
#pragma unroll
  for (int t = 0; t < 2; ++t) {
    int f4 = lane + 64 * t;
    f32x4 x = xr[f4], uu = ur[f4], vv = vr[f4];
    a1 += x[0]*uu[0] + x[1]*uu[1] + x[2]*uu[2] + x[3]*uu[3];
    a2 += x[0]*vv[0] + x[1]*vv[1] + x[2]*vv[2] + x[3]*vv[3];
  }
  for (int o = 32; o; o >>= 1) { a1 += __shfl_down(a1, o); a2 += __shfl_down(a2, o); }
  if (!lane) { sj[row] = a1; si[row] = a2; }
}

// tiled transpose -> bf16; optionally also emits the non-transposed bf16 copy.
// per slice: in R x C -> out C x R (and out2 R x C).  grid=(C/64, R/64, slices)
template <typename TI>
__global__ void trans_bf16_k(const TI* __restrict__ in, u16* __restrict__ out,
                             u16* __restrict__ out2, int R, int C) {
  __shared__ u16 tile[64][65];
  const TI* inS = in + (size_t)blockIdx.z * R * C;
  u16* outS = out + (size_t)blockIdx.z * R * C;
  int r0 = blockIdx.y * 64, c0 = blockIdx.x * 64;
  int t = threadIdx.x;
#pragma unroll
  for (int p = 0; p < 4; ++p) {
    int g = t + p * 256;
    int r = g >> 4, c4 = (g & 15) << 2;
    const TI* src = inS + (size_t)(r0 + r) * C + c0 + c4;
    u16x4v bv4;
    if constexpr (sizeof(TI) == 4) {
      f32x4 x = *(const f32x4*)src;
      bv4[0] = f2b(x[0]); bv4[1] = f2b(x[1]); bv4[2] = f2b(x[2]); bv4[3] = f2b(x[3]);
    } else {
      bv4 = *(const u16x4v*)src;
    }
    tile[r][c4+0] = bv4[0]; tile[r][c4+1] = bv4[1];
    tile[r][c4+2] = bv4[2]; tile[r][c4+3] = bv4[3];
    if (out2) {
      *(u16x4v*)(out2 + (size_t)blockIdx.z * R * C + (size_t)(r0 + r) * C + c0 + c4) = bv4;
    }
  }
  __syncthreads();
#pragma unroll
  for (int p = 0; p < 4; ++p) {
    int g = t + p * 256;
    int oc = g >> 4, o4 = (g & 15) << 2;
    u16x4v wv;
    wv[0] = tile[o4+0][oc]; wv[1] = tile[o4+1][oc];
    wv[2] = tile[o4+2][oc]; wv[3] = tile[o4+3][oc];
    *(u16x4v*)(outS + (size_t)(c0 + oc) * R + r0 + o4) = wv;
  }
}

// one wave per row: denom + transition (bf16), alpha kept in registers (32 VGPR).
__global__ void tmat_kernel(const float* __restrict__ Aa, const float* __restrict__ sj,
                            const float* __restrict__ si, const float* __restrict__ ccp,
                            u16* __restrict__ T, int rowbase) {
  int wid = threadIdx.x >> 6, lane = threadIdx.x & 63;
  int lr = blockIdx.x * 4 + wid;
  int gi = rowbase + lr;
  int b = gi >> 11;
  float siv = si[gi] + ccp[0];
  const f32x4* Arow = (const f32x4*)(Aa + (size_t)gi * NN);
  const f32x4* sjr = (const f32x4*)(sj + (size_t)b * NN);
  f32x4 al[8];
  float sum = 0.f;
#pragma unroll
  for (int t = 0; t < 8; ++t) {
    int f4 = lane + 64 * t;
    f32x4 a = Arow[f4];
    f32x4 s = sjr[f4];
#pragma unroll
    for (int j = 0; j < 4; ++j) {
      float e = s[j] + siv;
      e = e > 0.f ? e : 0.2f * e;
      al[t][j] = a[j] * __expf(e);
      sum += al[t][j];
    }
  }
#pragma unroll
  for (int o = 1; o < 64; o <<= 1) sum += __shfl_xor(sum, o);
  float rden = 1.0f / (sum + 1e-12f);
  u16* Trow = T + (size_t)lr * NN;
#pragma unroll
  for (int t = 0; t < 8; ++t) {
    int f4 = lane + 64 * t;
    u16x4v o4;
#pragma unroll
    for (int j = 0; j < 4; ++j) o4[j] = f2b(al[t][j] * rden);
    *(u16x4v*)(Trow + 4 * f4) = o4;
  }
}

// ---- GEMM: 128x64 tile, BK=64, 2-buffer dbuf, 1 syncthreads/iter, no remap ----
struct GemmP {
  const u16 *A0, *A1, *A2;   // row-major M x Kc (per source)
  const u16 *B0, *B1, *B2;   // row-major N x Kc  (B transposed)
  const float* bias;
  void* out;
  u16* outT;                 // optional transposed bf16 output (ldOT = M-dim)
  int ldA, ldB, ldO, ldOT;
  size_t batchA, batchB, batchOut, batchOutT;
};

__device__ __forceinline__ void gload16(const u16* g, const u16* l) {
  __builtin_amdgcn_global_load_lds((const __attribute__((address_space(1))) void*)g,
                                   (__attribute__((address_space(3))) void*)l, 16, 0, 0);
}

// chunk-XOR swizzled LDS: global (row, c8) stored at LDS chunk row*8 + (c8 ^ (row&7)).
template <int NSRC, int KT, bool OBF, bool OTR>
__launch_bounds__(256)
__global__ void gemm_k(GemmP p) {
  __shared__ u16 As[2][128 * 64];
  __shared__ u16 Bs[2][64 * 64];
  int tid = threadIdx.x;
  int lane = tid & 63;
  int w = tid >> 6;
  int wr = w >> 1, wc = w & 1;
  int bm = blockIdx.x, bn = blockIdx.y, bz = blockIdx.z;
  const u16* Alist[3] = {p.A0, p.A1, p.A2};
  const u16* Blist[3] = {p.B0, p.B1, p.B2};
  int rof = lane & 15, ksel = lane >> 4, sw = lane & 7;
  int wub = (tid & 192) * 8;  // wave-uniform chunk base (elems) within a 256-chunk group
  f32x4 acc[4][2] = {};

  auto stage = [&](int t, int buf) {
    int s = t / KT;
    int k0 = (t - s * KT) * 64;
    const u16* Ag = Alist[s] + (size_t)bz * p.batchA + (size_t)bm * 128 * p.ldA;
    const u16* Bg = Blist[s] + (size_t)bz * p.batchB + (size_t)bn * 64 * p.ldB;
#pragma unroll
    for (int q = 0; q < 4; ++q) {
      int ch = q * 256 + tid;
      int row = ch >> 3;
      int c8 = (ch & 7) ^ (row & 7);
      gload16(Ag + (size_t)row * p.ldA + k0 + c8 * 8, &As[buf][0] + q * 2048 + wub);
    }
#pragma unroll
    for (int q = 0; q < 2; ++q) {
      int ch = q * 256 + tid;
      int row = ch >> 3;
      int c8 = (ch & 7) ^ (row & 7);
      gload16(Bg + (size_t)row * p.ldB + k0 + c8 * 8, &Bs[buf][0] + q * 2048 + wub);
    }
  };

  constexpr int TOT = NSRC * KT;
  stage(0, 0);
  __syncthreads();
  int cur = 0;
  for (int t = 0; t < TOT; ++t) {
    if (t + 1 < TOT) stage(t + 1, cur ^ 1);
    const u16* Asb = &As[cur][0];
    const u16* Bsb = &Bs[cur][0];
#pragma unroll
    for (int kk = 0; kk < 2; ++kk) {
      int csw = ((kk * 4 + ksel) ^ sw) * 8;
      s16x8 af[4], bfr[2];
#pragma unroll
      for (int mf = 0; mf < 4; ++mf) {
        int r = wr * 64 + mf * 16 + rof;
        af[mf] = *(const s16x8*)(Asb + r * 64 + csw);
      }
#pragma unroll
      for (int nf = 0; nf < 2; ++nf) {
        int r = wc * 32 + nf * 16 + rof;
        bfr[nf] = *(const s16x8*)(Bsb + r * 64 + csw);
      }
#pragma unroll
      for (int mf = 0; mf < 4; ++mf)
#pragma unroll
        for (int nf = 0; nf < 2; ++nf)
          acc[mf][nf] = __builtin_amdgcn_mfma_f32_16x16x32_bf16(af[mf], bfr[nf], acc[mf][nf], 0, 0, 0);
    }
    __syncthreads();
    cur ^= 1;
  }

  int rb = bm * 128 + wr * 64, cb = bn * 64 + wc * 32;
  int rsub = ksel << 2, csub = rof;
  if constexpr (OBF) {
    u16* o = (u16*)p.out + (size_t)bz * p.batchOut;
    u16* oT = OTR ? p.outT + (size_t)bz * p.batchOutT : nullptr;
#pragma unroll
    for (int mf = 0; mf < 4; ++mf)
#pragma unroll
      for (int nf = 0; nf < 2; ++nf) {
        int cidx = cb + nf * 16 + csub;
        u16x4v tv;
#pragma unroll
        for (int r = 0; r < 4; ++r) {
          tv[r] = f2b(acc[mf][nf][r]);
          o[(size_t)(rb + mf * 16 + rsub + r) * p.ldO + cidx] = tv[r];
        }
        if constexpr (OTR) {
          *(u16x4v*)(oT + (size_t)cidx * p.ldOT + rb + mf * 16 + rsub) = tv;
        }
      }
  } else {
    float* o = (float*)p.out + (size_t)bz * p.batchOut;
#pragma unroll
    for (int nf = 0; nf < 2; ++nf) {
      int cidx = cb + nf * 16 + csub;
      float bv_ = p.bias[cidx];
#pragma unroll
      for (int mf = 0; mf < 4; ++mf)
#pragma unroll
        for (int r = 0; r < 4; ++r) {
          float val = acc[mf][nf][r] + bv_;
          o[(size_t)(rb + mf * 16 + rsub + r) * p.ldO + cidx] = val > 0.f ? val : 0.f;
        }
    }
  }
}

// ---------------- launch ----------------
extern "C" void kernel_launch(void* const* d_in, const int* in_sizes, int n_in,
                              void* d_out, int out_size, void* d_ws, size_t ws_size,
                              hipStream_t stream) {
  const float* X  = (const float*)d_in[0];
  const float* A  = (const float*)d_in[1];
  const float* Wv = (const float*)d_in[2];
  const float* bv = (const float*)d_in[3];
  const float* aw = (const float*)d_in[4];
  const float* ab = (const float*)d_in[5];
  const float* Wk = (const float*)d_in[6];
  const float* bk = (const float*)d_in[7];
  float* out = (float*)d_out;

  char* ws = (char*)d_ws;
  size_t off = 0;
  auto alloc = [&](size_t bytes) -> void* {
    void* p = (void*)(ws + off);
    off = (off + bytes + 255) & ~(size_t)255;
    return p;
  };
  float* u    = (float*)alloc(DI * 4);
  float* v    = (float*)alloc(DI * 4);
  float* cc   = (float*)alloc(256);
  float* bsum = (float*)alloc(DOUTC * 4);
  float* sj   = (float*)alloc((size_t)NB * NN * 4);
  float* si   = (float*)alloc((size_t)NB * NN * 4);
  u16* WkT  = (u16*)alloc((size_t)KP * DI * DOUTC * 2);
  u16* Xb   = (u16*)alloc((size_t)NB * NN * DI * 2);
  u16* XbT  = (u16*)alloc((size_t)NB * NN * DI * 2);
  u16* X1b  = (u16*)alloc((size_t)NB * NN * DOUTC * 2);
  u16* X1bT = (u16*)alloc((size_t)NB * NN * DOUTC * 2);
  u16* X2b  = (u16*)alloc((size_t)NB * NN * DOUTC * 2);
  size_t fixedEnd = off;
  int G = 4;
  while (G > 1 && fixedEnd + (size_t)G * NN * NN * 2 > ws_size) G >>= 1;
  u16* Tb = (u16*)alloc((size_t)G * NN * NN * 2);

  prep_uv<<<2, 256, 0, stream>>>(Wv, aw, bk, u, v, bsum);
  prep_cc<<<1, 64, 0, stream>>>(bv, aw, ab, cc);
  trans_bf16_k<float><<<dim3(8, 8, 3), 256, 0, stream>>>(Wk, WkT, nullptr, 512, 512);
  // X: one read -> XbT (transposed bf16) + Xb (row-major bf16)
  trans_bf16_k<float><<<dim3(8, 32, 4), 256, 0, stream>>>(X, XbT, Xb, NN, DI);
  sjsi_kernel<<<NB * NN / 4, 256, 0, stream>>>(X, u, v, sj, si);

  for (int g0 = 0; g0 < NB; g0 += G) {
    tmat_kernel<<<G * NN / 4, 256, 0, stream>>>(A, sj, si, cc, Tb, g0 * NN);

    GemmP p1{};
    p1.A0 = p1.A1 = p1.A2 = Tb;
    p1.B0 = p1.B1 = p1.B2 = XbT + (size_t)g0 * DI * NN;
    p1.bias = nullptr;
    p1.out = X1b + (size_t)g0 * NN * DOUTC;
    p1.outT = X1bT + (size_t)g0 * DOUTC * NN;
    p1.ldA = NN; p1.ldB = NN; p1.ldO = DOUTC; p1.ldOT = NN;
    p1.batchA = (size_t)NN * NN; p1.batchB = (size_t)DI * NN;
    p1.batchOut = (size_t)NN * DOUTC; p1.batchOutT = (size_t)DOUTC * NN;
    gemm_k<1, 32, true, true><<<dim3(16, 8, G), 256, 0, stream>>>(p1);

    GemmP p2 = p1;
    p2.B0 = p2.B1 = p2.B2 = X1bT + (size_t)g0 * DOUTC * NN;
    p2.out = X2b + (size_t)g0 * NN * DOUTC;
    p2.outT = nullptr;
    gemm_k<1, 32, true, false><<<dim3(16, 8, G), 256, 0, stream>>>(p2);
  }

  GemmP p3{};
  p3.A0 = Xb; p3.A1 = X1b; p3.A2 = X2b;
  p3.B0 = WkT; p3.B1 = WkT + (size_t)DI * DOUTC; p3.B2 = WkT + (size_t)2 * DI * DOUTC;
  p3.bias = bsum; p3.out = out; p3.outT = nullptr;
  p3.ldA = DI; p3.ldB = DI; p3.ldO = DOUTC; p3.ldOT = 0;
  p3.batchA = 0; p3.batchB = 0; p3.batchOut = 0; p3.batchOutT = 0;
  gemm_k<3, 8, false, false><<<dim3(64, 8, 1), 256, 0, stream>>>(p3);
}

// Round 6
// 135.948 us; speedup vs baseline: 1.2496x; 1.0454x over previous
//
#include <hip/hip_runtime.h>

typedef float f32x4 __attribute__((ext_vector_type(4)));
typedef short s16x8 __attribute__((ext_vector_type(8)));
typedef unsigned short u16;
typedef u16 u16x4v __attribute__((ext_vector_type(4)));
typedef u16 u16x8v __attribute__((ext_vector_type(8)));

#define NB 4
#define NN 2048
#define DI 512
#define DOUTC 512
#define KP 3

__device__ __forceinline__ u16 f2b(float f) {
  unsigned u = __builtin_bit_cast(unsigned, f);
  unsigned r = u + 0x7fffu + ((u >> 16) & 1u);
  return (u16)(r >> 16);
}

// ---------------- prep kernels ----------------
__global__ void prep_uv(const float* __restrict__ Wv, const float* __restrict__ aw,
                        const float* __restrict__ bk, float* u, float* v, float* bsum) {
  int c = blockIdx.x * blockDim.x + threadIdx.x;
  if (c >= DI) return;
  float a1 = 0.f, a2 = 0.f;
  const float* row = Wv + (size_t)c * DOUTC;
  for (int d = 0; d < DOUTC; ++d) {
    float w = row[d];
    a1 += w * aw[d];
    a2 += w * aw[DOUTC + d];
  }
  u[c] = a1; v[c] = a2;
  bsum[c] = bk[c] + bk[DOUTC + c] + bk[2 * DOUTC + c];
}

__global__ void prep_cc(const float* __restrict__ bv, const float* __restrict__ aw,
                        const float* __restrict__ ab, float* cc) {
  int l = threadIdx.x;
  float s = 0.f;
  for (int d = l; d < DOUTC; d += 64) s += bv[d] * (aw[d] + aw[DOUTC + d]);
  for (int o = 32; o; o >>= 1) s += __shfl_down(s, o);
  if (l == 0) cc[0] = s + ab[0];
}

// sj[b,i] = X[b,i,:].u ; si[b,i] = X[b,i,:].v   (one wave per row, f32 inputs)
__global__ void sjsi_kernel(const float* __restrict__ X, const float* __restrict__ u,
                            const float* __restrict__ v, float* sj, float* si) {
  int wid = threadIdx.x >> 6, lane = threadIdx.x & 63;
  int row = blockIdx.x * 4 + wid;
  const f32x4* xr = (const f32x4*)(X + (size_t)row * DI);
  const f32x4* ur = (const f32x4*)u;
  const f32x4* vr = (const f32x4*)v;
  float a1 = 0.f, a2 = 0.f;
#pragma unroll
  for (int t = 0; t < 2; ++t) {
    int f4 = lane + 64 * t;
    f32x4 x = xr[f4], uu = ur[f4], vv = vr[f4];
    a1 += x[0]*uu[0] + x[1]*uu[1] + x[2]*uu[2] + x[3]*uu[3];
    a2 += x[0]*vv[0] + x[1]*vv[1] + x[2]*vv[2] + x[3]*vv[3];
  }
  for (int o = 32; o; o >>= 1) { a1 += __shfl_down(a1, o); a2 += __shfl_down(a2, o); }
  if (!lane) { sj[row] = a1; si[row] = a2; }
}

// tiled transpose -> bf16; optionally also emits the non-transposed bf16 copy.
// per slice: in R x C -> out C x R (and out2 R x C).  grid=(C/64, R/64, slices)
template <typename TI>
__global__ void trans_bf16_k(const TI* __restrict__ in, u16* __restrict__ out,
                             u16* __restrict__ out2, int R, int C) {
  __shared__ u16 tile[64][65];
  const TI* inS = in + (size_t)blockIdx.z * R * C;
  u16* outS = out + (size_t)blockIdx.z * R * C;
  int r0 = blockIdx.y * 64, c0 = blockIdx.x * 64;
  int t = threadIdx.x;
#pragma unroll
  for (int p = 0; p < 4; ++p) {
    int g = t + p * 256;
    int r = g >> 4, c4 = (g & 15) << 2;
    const TI* src = inS + (size_t)(r0 + r) * C + c0 + c4;
    u16x4v bv4;
    if constexpr (sizeof(TI) == 4) {
      f32x4 x = *(const f32x4*)src;
      bv4[0] = f2b(x[0]); bv4[1] = f2b(x[1]); bv4[2] = f2b(x[2]); bv4[3] = f2b(x[3]);
    } else {
      bv4 = *(const u16x4v*)src;
    }
    tile[r][c4+0] = bv4[0]; tile[r][c4+1] = bv4[1];
    tile[r][c4+2] = bv4[2]; tile[r][c4+3] = bv4[3];
    if (out2) {
      *(u16x4v*)(out2 + (size_t)blockIdx.z * R * C + (size_t)(r0 + r) * C + c0 + c4) = bv4;
    }
  }
  __syncthreads();
#pragma unroll
  for (int p = 0; p < 4; ++p) {
    int g = t + p * 256;
    int oc = g >> 4, o4 = (g & 15) << 2;
    u16x4v wv;
    wv[0] = tile[o4+0][oc]; wv[1] = tile[o4+1][oc];
    wv[2] = tile[o4+2][oc]; wv[3] = tile[o4+3][oc];
    *(u16x4v*)(outS + (size_t)(c0 + oc) * R + r0 + o4) = wv;
  }
}

// one wave per row: denom + transition (bf16), alpha kept in registers (32 VGPR).
__global__ void tmat_kernel(const float* __restrict__ Aa, const float* __restrict__ sj,
                            const float* __restrict__ si, const float* __restrict__ ccp,
                            u16* __restrict__ T, int rowbase) {
  int wid = threadIdx.x >> 6, lane = threadIdx.x & 63;
  int lr = blockIdx.x * 4 + wid;
  int gi = rowbase + lr;
  int b = gi >> 11;
  float siv = si[gi] + ccp[0];
  const f32x4* Arow = (const f32x4*)(Aa + (size_t)gi * NN);
  const f32x4* sjr = (const f32x4*)(sj + (size_t)b * NN);
  f32x4 al[8];
  float sum = 0.f;
#pragma unroll
  for (int t = 0; t < 8; ++t) {
    int f4 = lane + 64 * t;
    f32x4 a = Arow[f4];
    f32x4 s = sjr[f4];
#pragma unroll
    for (int j = 0; j < 4; ++j) {
      float e = s[j] + siv;
      e = e > 0.f ? e : 0.2f * e;
      al[t][j] = a[j] * __expf(e);
      sum += al[t][j];
    }
  }
#pragma unroll
  for (int o = 1; o < 64; o <<= 1) sum += __shfl_xor(sum, o);
  float rden = 1.0f / (sum + 1e-12f);
  u16* Trow = T + (size_t)lr * NN;
#pragma unroll
  for (int t = 0; t < 8; ++t) {
    int f4 = lane + 64 * t;
    u16x4v o4;
#pragma unroll
    for (int j = 0; j < 4; ++j) o4[j] = f2b(al[t][j] * rden);
    *(u16x4v*)(Trow + 4 * f4) = o4;
  }
}

// ---- GEMM: 128x64 tile, BK=64, 3-buffer counted-vmcnt(6) pipeline (round-3
// proven loop), natural block order + BK64 swizzle + scatter-OT (round-4 proven) ----
struct GemmP {
  const u16 *A0, *A1, *A2;   // row-major M x Kc (per source)
  const u16 *B0, *B1, *B2;   // row-major N x Kc  (B transposed)
  const float* bias;
  void* out;
  u16* outT;                 // optional transposed bf16 output (ldOT = M-dim)
  int ldA, ldB, ldO, ldOT;
  size_t batchA, batchB, batchOut, batchOutT;
};

__device__ __forceinline__ void gload16(const u16* g, const u16* l) {
  __builtin_amdgcn_global_load_lds((const __attribute__((address_space(1))) void*)g,
                                   (__attribute__((address_space(3))) void*)l, 16, 0, 0);
}

// chunk-XOR swizzled LDS: global (row, c8) stored at LDS chunk row*8 + (c8 ^ (row&7)).
template <int NSRC, int KT, bool OBF, bool OTR>
__launch_bounds__(256)
__global__ void gemm_k(GemmP p) {
  __shared__ u16 As[3][128 * 64];
  __shared__ u16 Bs[3][64 * 64];
  int tid = threadIdx.x;
  int lane = tid & 63;
  int w = tid >> 6;
  int wr = w >> 1, wc = w & 1;
  int bm = blockIdx.x, bn = blockIdx.y, bz = blockIdx.z;
  const u16* Alist[3] = {p.A0, p.A1, p.A2};
  const u16* Blist[3] = {p.B0, p.B1, p.B2};
  int rof = lane & 15, ksel = lane >> 4, sw = lane & 7;
  int wub = (tid & 192) * 8;  // wave-uniform chunk base (elems) within a 256-chunk group
  f32x4 acc[4][2] = {};

  auto stage = [&](int t, int buf) {
    int s = t / KT;
    int k0 = (t - s * KT) * 64;
    const u16* Ag = Alist[s] + (size_t)bz * p.batchA + (size_t)bm * 128 * p.ldA;
    const u16* Bg = Blist[s] + (size_t)bz * p.batchB + (size_t)bn * 64 * p.ldB;
#pragma unroll
    for (int q = 0; q < 4; ++q) {
      int ch = q * 256 + tid;
      int row = ch >> 3;
      int c8 = (ch & 7) ^ (row & 7);
      gload16(Ag + (size_t)row * p.ldA + k0 + c8 * 8, &As[buf][0] + q * 2048 + wub);
    }
#pragma unroll
    for (int q = 0; q < 2; ++q) {
      int ch = q * 256 + tid;
      int row = ch >> 3;
      int c8 = (ch & 7) ^ (row & 7);
      gload16(Bg + (size_t)row * p.ldB + k0 + c8 * 8, &Bs[buf][0] + q * 2048 + wub);
    }
  };

  constexpr int TOT = NSRC * KT;
  stage(0, 0);
  stage(1, 1);
  asm volatile("s_waitcnt vmcnt(6)" ::: "memory");
  __builtin_amdgcn_s_barrier();
  __builtin_amdgcn_sched_barrier(0);

  int bufc = 0;
  for (int t = 0; t < TOT; ++t) {
    int nb = t + 2;
    if (nb < TOT) stage(nb, bufc == 0 ? 2 : bufc - 1);
    const u16* Asb = &As[bufc][0];
    const u16* Bsb = &Bs[bufc][0];
#pragma unroll
    for (int kk = 0; kk < 2; ++kk) {
      int csw = ((kk * 4 + ksel) ^ sw) * 8;
      s16x8 af[4], bfr[2];
#pragma unroll
      for (int mf = 0; mf < 4; ++mf) {
        int r = wr * 64 + mf * 16 + rof;
        af[mf] = *(const s16x8*)(Asb + r * 64 + csw);
      }
#pragma unroll
      for (int nf = 0; nf < 2; ++nf) {
        int r = wc * 32 + nf * 16 + rof;
        bfr[nf] = *(const s16x8*)(Bsb + r * 64 + csw);
      }
#pragma unroll
      for (int mf = 0; mf < 4; ++mf)
#pragma unroll
        for (int nf = 0; nf < 2; ++nf)
          acc[mf][nf] = __builtin_amdgcn_mfma_f32_16x16x32_bf16(af[mf], bfr[nf], acc[mf][nf], 0, 0, 0);
    }
    if (nb < TOT) {
      asm volatile("s_waitcnt vmcnt(6)" ::: "memory");   // stage(t+1) landed; t+2 in flight
    } else if (t + 1 < TOT) {
      asm volatile("s_waitcnt vmcnt(0)" ::: "memory");   // tail: drain last stage
    }
    if (t + 1 < TOT) {
      __builtin_amdgcn_s_barrier();
      __builtin_amdgcn_sched_barrier(0);
    }
    bufc = bufc + 1; if (bufc == 3) bufc = 0;
  }

  int rb = bm * 128 + wr * 64, cb = bn * 64 + wc * 32;
  int rsub = ksel << 2, csub = rof;
  if constexpr (OBF) {
    u16* o = (u16*)p.out + (size_t)bz * p.batchOut;
    u16* oT = OTR ? p.outT + (size_t)bz * p.batchOutT : nullptr;
#pragma unroll
    for (int mf = 0; mf < 4; ++mf)
#pragma unroll
      for (int nf = 0; nf < 2; ++nf) {
        int cidx = cb + nf * 16 + csub;
        u16x4v tv;
#pragma unroll
        for (int r = 0; r < 4; ++r) {
          tv[r] = f2b(acc[mf][nf][r]);
          o[(size_t)(rb + mf * 16 + rsub + r) * p.ldO + cidx] = tv[r];
        }
        if constexpr (OTR) {
          *(u16x4v*)(oT + (size_t)cidx * p.ldOT + rb + mf * 16 + rsub) = tv;
        }
      }
  } else {
    float* o = (float*)p.out + (size_t)bz * p.batchOut;
#pragma unroll
    for (int nf = 0; nf < 2; ++nf) {
      int cidx = cb + nf * 16 + csub;
      float bv_ = p.bias[cidx];
#pragma unroll
      for (int mf = 0; mf < 4; ++mf)
#pragma unroll
        for (int r = 0; r < 4; ++r) {
          float val = acc[mf][nf][r] + bv_;
          o[(size_t)(rb + mf * 16 + rsub + r) * p.ldO + cidx] = val > 0.f ? val : 0.f;
        }
    }
  }
}

// ---------------- launch ----------------
extern "C" void kernel_launch(void* const* d_in, const int* in_sizes, int n_in,
                              void* d_out, int out_size, void* d_ws, size_t ws_size,
                              hipStream_t stream) {
  const float* X  = (const float*)d_in[0];
  const float* A  = (const float*)d_in[1];
  const float* Wv = (const float*)d_in[2];
  const float* bv = (const float*)d_in[3];
  const float* aw = (const float*)d_in[4];
  const float* ab = (const float*)d_in[5];
  const float* Wk = (const float*)d_in[6];
  const float* bk = (const float*)d_in[7];
  float* out = (float*)d_out;

  char* ws = (char*)d_ws;
  size_t off = 0;
  auto alloc = [&](size_t bytes) -> void* {
    void* p = (void*)(ws + off);
    off = (off + bytes + 255) & ~(size_t)255;
    return p;
  };
  float* u    = (float*)alloc(DI * 4);
  float* v    = (float*)alloc(DI * 4);
  float* cc   = (float*)alloc(256);
  float* bsum = (float*)alloc(DOUTC * 4);
  float* sj   = (float*)alloc((size_t)NB * NN * 4);
  float* si   = (float*)alloc((size_t)NB * NN * 4);
  u16* WkT  = (u16*)alloc((size_t)KP * DI * DOUTC * 2);
  u16* Xb   = (u16*)alloc((size_t)NB * NN * DI * 2);
  u16* XbT  = (u16*)alloc((size_t)NB * NN * DI * 2);
  u16* X1b  = (u16*)alloc((size_t)NB * NN * DOUTC * 2);
  u16* X1bT = (u16*)alloc((size_t)NB * NN * DOUTC * 2);
  u16* X2b  = (u16*)alloc((size_t)NB * NN * DOUTC * 2);
  size_t fixedEnd = off;
  int G = 4;
  while (G > 1 && fixedEnd + (size_t)G * NN * NN * 2 > ws_size) G >>= 1;
  u16* Tb = (u16*)alloc((size_t)G * NN * NN * 2);

  prep_uv<<<2, 256, 0, stream>>>(Wv, aw, bk, u, v, bsum);
  prep_cc<<<1, 64, 0, stream>>>(bv, aw, ab, cc);
  trans_bf16_k<float><<<dim3(8, 8, 3), 256, 0, stream>>>(Wk, WkT, nullptr, 512, 512);
  // X: one read -> XbT (transposed bf16) + Xb (row-major bf16)
  trans_bf16_k<float><<<dim3(8, 32, 4), 256, 0, stream>>>(X, XbT, Xb, NN, DI);
  sjsi_kernel<<<NB * NN / 4, 256, 0, stream>>>(X, u, v, sj, si);

  for (int g0 = 0; g0 < NB; g0 += G) {
    tmat_kernel<<<G * NN / 4, 256, 0, stream>>>(A, sj, si, cc, Tb, g0 * NN);

    GemmP p1{};
    p1.A0 = p1.A1 = p1.A2 = Tb;
    p1.B0 = p1.B1 = p1.B2 = XbT + (size_t)g0 * DI * NN;
    p1.bias = nullptr;
    p1.out = X1b + (size_t)g0 * NN * DOUTC;
    p1.outT = X1bT + (size_t)g0 * DOUTC * NN;
    p1.ldA = NN; p1.ldB = NN; p1.ldO = DOUTC; p1.ldOT = NN;
    p1.batchA = (size_t)NN * NN; p1.batchB = (size_t)DI * NN;
    p1.batchOut = (size_t)NN * DOUTC; p1.batchOutT = (size_t)DOUTC * NN;
    gemm_k<1, 32, true, true><<<dim3(16, 8, G), 256, 0, stream>>>(p1);

    GemmP p2 = p1;
    p2.B0 = p2.B1 = p2.B2 = X1bT + (size_t)g0 * DOUTC * NN;
    p2.out = X2b + (size_t)g0 * NN * DOUTC;
    p2.outT = nullptr;
    gemm_k<1, 32, true, false><<<dim3(16, 8, G), 256, 0, stream>>>(p2);
  }

  GemmP p3{};
  p3.A0 = Xb; p3.A1 = X1b; p3.A2 = X2b;
  p3.B0 = WkT; p3.B1 = WkT + (size_t)DI * DOUTC; p3.B2 = WkT + (size_t)2 * DI * DOUTC;
  p3.bias = bsum; p3.out = out; p3.outT = nullptr;
  p3.ldA = DI; p3.ldB = DI; p3.ldO = DOUTC; p3.ldOT = 0;
  p3.batchA = 0; p3.batchB = 0; p3.batchOut = 0; p3.batchOutT = 0;
  gemm_k<3, 8, false, false><<<dim3(64, 8, 1), 256, 0, stream>>>(p3);
}